// Round 7
// baseline (195.232 us; speedup 1.0000x reference)
//
#include <hip/hip_runtime.h>
#include <stdint.h>

typedef unsigned short u16;
typedef unsigned int u32;

#define N_NODES 2708
#define IN_C    2048
#define OUT_C   512
#define MP      2816   // padded node count (multiple of 128)
#define KP      2816   // padded K for gemm2 (= MP)

using floatx4 = __attribute__((ext_vector_type(4))) float;
using short8  = __attribute__((ext_vector_type(8))) short;

// ---- workspace layout (32.4 MB total) ----
constexpr size_t XB_OFF = 0;
constexpr size_t XB_SZ  = (size_t)MP * IN_C * 2;      // 11,534,336
constexpr size_t WB_OFF = XB_OFF + XB_SZ;
constexpr size_t WB_SZ  = (size_t)OUT_C * IN_C * 2;   //  2,097,152
constexpr size_t HT_OFF = WB_OFF + WB_SZ;
constexpr size_t HT_SZ  = (size_t)OUT_C * MP * 2;     //  2,883,584
constexpr size_t AC_OFF = HT_OFF + HT_SZ;             // 16,515,072 (16B aligned)
constexpr size_t AC_SZ  = (size_t)MP * KP * 2;        // 15,859,712

static __device__ __forceinline__ u16 f2bf(float f) {
  union { float f; u32 u; } v; v.f = f;
  u32 r = v.u + 0x7fffu + ((v.u >> 16) & 1u);  // RNE
  return (u16)(r >> 16);
}

// ---- fused prep: x -> bf16 (padded rows), w -> bf16, zero Ac ----
constexpr int XBLK = MP * IN_C / 8 / 256;              // 2816 (block b == row b)
constexpr int WBLK = OUT_C * IN_C / 8 / 256;           // 512
constexpr int ZF4  = (int)(AC_SZ / 16);                // 991,232
constexpr int ZBLK = ZF4 / 256;                        // 3872 (exact)
constexpr int PREP_BLK = XBLK + WBLK + ZBLK;           // 7200

__global__ void k_prep(const float* __restrict__ x, const float* __restrict__ w,
                       u16* __restrict__ xb, u16* __restrict__ wb,
                       float4* __restrict__ zac) {
  const int b = blockIdx.x, tid = threadIdx.x;
  if (b < XBLK) {
    const int row = b, col = tid * 8;
    union { u16 u[8]; uint4 v; } o;
    if (row < N_NODES) {
      float4 v0 = *(const float4*)&x[(size_t)row * IN_C + col];
      float4 v1 = *(const float4*)&x[(size_t)row * IN_C + col + 4];
      o.u[0]=f2bf(v0.x); o.u[1]=f2bf(v0.y); o.u[2]=f2bf(v0.z); o.u[3]=f2bf(v0.w);
      o.u[4]=f2bf(v1.x); o.u[5]=f2bf(v1.y); o.u[6]=f2bf(v1.z); o.u[7]=f2bf(v1.w);
    } else {
      o.v = make_uint4(0, 0, 0, 0);
    }
    *(uint4*)&xb[(size_t)row * IN_C + col] = o.v;
  } else if (b < XBLK + WBLK) {
    const int idx = ((b - XBLK) * 256 + tid) * 8;
    float4 v0 = *(const float4*)&w[idx];
    float4 v1 = *(const float4*)&w[idx + 4];
    union { u16 u[8]; uint4 v; } o;
    o.u[0]=f2bf(v0.x); o.u[1]=f2bf(v0.y); o.u[2]=f2bf(v0.z); o.u[3]=f2bf(v0.w);
    o.u[4]=f2bf(v1.x); o.u[5]=f2bf(v1.y); o.u[6]=f2bf(v1.z); o.u[7]=f2bf(v1.w);
    *(uint4*)&wb[idx] = o.v;
  } else {
    const int i = (b - XBLK - WBLK) * 256 + tid;
    zac[i] = make_float4(0.f, 0.f, 0.f, 0.f);
  }
}

// ---- edge counts into u16 halfwords via u32 atomics ----
__global__ void k_count(const int* __restrict__ ei, u32* __restrict__ Ac, int E) {
  int e = blockIdx.x * 256 + threadIdx.x;
  if (e < E) {
    int src = ei[e];
    int dst = ei[E + e];
    u32 idx = (u32)dst * KP + (u32)src;  // u16 element index
    atomicAdd(&Ac[idx >> 1], 1u << ((idx & 1) * 16));
  }
}

// ---- in-place u16 count -> bf16 (exact for counts <= 256) ----
static __device__ __forceinline__ u32 cvt2(u32 w) {
  float lo = (float)(w & 0xffffu), hi = (float)(w >> 16);
  return (u32)f2bf(lo) | ((u32)f2bf(hi) << 16);
}
__global__ void k_cvtA(uint4* __restrict__ A, int n) {
  int i = blockIdx.x * 256 + threadIdx.x;
  if (i < n) {
    uint4 v = A[i];
    A[i] = make_uint4(cvt2(v.x), cvt2(v.y), cvt2(v.z), cvt2(v.w));
  }
}

// ---- GEMM: C[m][n] = sum_k A[m][k]*B[n][k] (+bias), bf16 row-major, ld=LDK.
// BM=128 BN=128 BK=64, 4 waves 2x2, wave-tile 64x64 (acc[4][4]) -- the
// LDS/MFMA balance point (0.5 b128/MFMA). Grid 88 (22 bm x 4 bn); staging
// redundancy A x4 + B x22 = ~127 MB L2-side (R6's 64x32 tiles: 381 MB, the
// measured ~50 us/GEMM wall). T4 counted-vmcnt pipeline: 3 LDS buffers,
// STAGE 2 ahead, s_waitcnt vmcnt(8) mid-loop (8 loads/stage/thread).
// T2 both-sides swizzle (rule #21), XCD-bijective swizzle (88 % 8 == 0),
// T5 setprio around MFMA.
// EPI=0: dst = hT bf16 [OUT_C][MP], writes f2bf(acc + bias[n]) transposed.
// EPI=1: dst = out f32 [N_NODES][OUT_C], plain stores, m < N_NODES guard.
template<int LDK, int NKI, int EPI>
__global__ __launch_bounds__(256, 1) void k_gemm(
    const u16* __restrict__ A, const u16* __restrict__ B,
    const float* __restrict__ bias, void* __restrict__ dst) {
  __shared__ u16 lA[3][128 * 64];
  __shared__ u16 lB[3][128 * 64];
  const int tid = threadIdx.x, lane = tid & 63, wid = tid >> 6;

  // XCD swizzle: orig on XCD x -> swz = x*11 + j (consecutive per XCD);
  // per-XCD working set: ~3 A-panels (2.2 MB) + B panels -> mostly L2.
  const int cpx = (int)gridDim.x >> 3;          // 11
  const int orig = blockIdx.x;
  const int swz = (orig & 7) * cpx + (orig >> 3);
  const int bn = swz & 3, bm = swz >> 2;
  const int bmr = bm * 128, bnr = bn * 128;

  const int wr = wid >> 1, wc = wid & 1;

  // staging: A tile 128x64 bf16 = 16 KB = 16 chunks of 1 KB (8 rows each);
  // wave w -> chunks {w+4j}; lane l -> row 8c+(l>>3), 16B slot (l&7)^(row&7).
  const int swzl = ((lane & 7) ^ ((lane >> 3) & 7)) * 16;
  const char* ag[4];
  const char* bg[4];
#pragma unroll
  for (int j = 0; j < 4; ++j) {
    int c = wid + 4 * j, row = 8 * c + (lane >> 3);
    ag[j] = (const char*)A + (size_t)(bmr + row) * (LDK * 2) + swzl;
    bg[j] = (const char*)B + (size_t)(bnr + row) * (LDK * 2) + swzl;
  }

  // 8 global_load_lds per thread per STAGE (4 A + 4 B) -> vmcnt units of 8
#define STAGE(bb, tt) do {                                                        \
  _Pragma("unroll")                                                               \
  for (int j = 0; j < 4; ++j) {                                                   \
    __builtin_amdgcn_global_load_lds(                                             \
      (const __attribute__((address_space(1))) u32*)(ag[j] + (size_t)(tt) * 128), \
      (__attribute__((address_space(3))) u32*)&lA[bb][(wid + 4 * j) * 512],       \
      16, 0, 0);                                                                  \
    __builtin_amdgcn_global_load_lds(                                             \
      (const __attribute__((address_space(1))) u32*)(bg[j] + (size_t)(tt) * 128), \
      (__attribute__((address_space(3))) u32*)&lB[bb][(wid + 4 * j) * 512],       \
      16, 0, 0);                                                                  \
  }                                                                               \
} while (0)

  floatx4 acc[4][4] = {};

  STAGE(0, 0);
  if (NKI > 1) STAGE(1, 1);
  int cur = 0;
  for (int t = 0; t < NKI; ++t) {
    // wait for stage(t) only: leaves stage(t+1)'s 8 loads in flight
    if (t + 1 < NKI) asm volatile("s_waitcnt vmcnt(8)" ::: "memory");
    else             asm volatile("s_waitcnt vmcnt(0)" ::: "memory");
    __builtin_amdgcn_s_barrier();
    asm volatile("" ::: "memory");           // fence: keep ds_reads below barrier
    if (t + 2 < NKI) {
      int nb = cur + 2; if (nb >= 3) nb -= 3;
      STAGE(nb, t + 2);                      // overwrites buf consumed at t-1: safe
    }
    const u16* pA = lA[cur];
    const u16* pB = lB[cur];
    short8 af[4][2], bf[4][2];
    // read-side swizzle: slot' = slot ^ (row&7); row&7 == lane&7 for A and B.
#pragma unroll
    for (int mi = 0; mi < 4; ++mi)
#pragma unroll
      for (int kk = 0; kk < 2; ++kk) {
        const int row = wr * 64 + mi * 16 + (lane & 15);
        const int col8 = ((kk * 4 + (lane >> 4)) ^ (lane & 7)) * 8;
        af[mi][kk] = *(const short8*)&pA[row * 64 + col8];
      }
#pragma unroll
    for (int ni = 0; ni < 4; ++ni)
#pragma unroll
      for (int kk = 0; kk < 2; ++kk) {
        const int row = wc * 64 + ni * 16 + (lane & 15);
        const int col8 = ((kk * 4 + (lane >> 4)) ^ (lane & 7)) * 8;
        bf[ni][kk] = *(const short8*)&pB[row * 64 + col8];
      }
    __builtin_amdgcn_s_setprio(1);
#pragma unroll
    for (int kk = 0; kk < 2; ++kk)
#pragma unroll
      for (int mi = 0; mi < 4; ++mi)
#pragma unroll
        for (int ni = 0; ni < 4; ++ni)
          acc[mi][ni] = __builtin_amdgcn_mfma_f32_16x16x32_bf16(af[mi][kk], bf[ni][kk], acc[mi][ni], 0, 0, 0);
    __builtin_amdgcn_s_setprio(0);
    ++cur; if (cur >= 3) cur -= 3;
  }
#undef STAGE

  const int lr = (lane >> 4) * 4, lc = lane & 15;
  if (EPI == 0) {
    u16* hTp = (u16*)dst;
#pragma unroll
    for (int ni = 0; ni < 4; ++ni) {
      const int n = bnr + wc * 64 + ni * 16 + lc;
      const float bv = bias[n];
#pragma unroll
      for (int mi = 0; mi < 4; ++mi) {
        const int m0 = bmr + wr * 64 + mi * 16 + lr;
        union { u16 u[4]; uint2 v; } o;
#pragma unroll
        for (int j = 0; j < 4; ++j) o.u[j] = f2bf(acc[mi][ni][j] + bv);
        *(uint2*)&hTp[(size_t)n * MP + m0] = o.v;
      }
    }
  } else {
    float* op = (float*)dst;
#pragma unroll
    for (int mi = 0; mi < 4; ++mi)
#pragma unroll
      for (int j = 0; j < 4; ++j) {
        const int m = bmr + wr * 64 + mi * 16 + lr + j;
        if (m < N_NODES) {
#pragma unroll
          for (int ni = 0; ni < 4; ++ni) {
            const int n = bnr + wc * 64 + ni * 16 + lc;
            op[(size_t)m * OUT_C + n] = acc[mi][ni][j];
          }
        }
      }
  }
}

extern "C" void kernel_launch(void* const* d_in, const int* in_sizes, int n_in,
                              void* d_out, int out_size, void* d_ws, size_t ws_size,
                              hipStream_t stream) {
  const float* x    = (const float*)d_in[0];
  const int*   ei   = (const int*)d_in[1];
  const float* w    = (const float*)d_in[2];
  const float* bias = (const float*)d_in[3];
  float* out = (float*)d_out;

  char* ws = (char*)d_ws;
  u16* xb = (u16*)(ws + XB_OFF);
  u16* wb = (u16*)(ws + WB_OFF);
  u16* hT = (u16*)(ws + HT_OFF);
  u16* Ac = (u16*)(ws + AC_OFF);   // u16 counts, then bf16 in-place

  const int E = in_sizes[1] / 2;  // 500000

  // prep: x->bf16(padded), w->bf16, zero Ac
  k_prep<<<dim3(PREP_BLK), dim3(256), 0, stream>>>(x, w, xb, wb, (float4*)Ac);
  // edge counts (u16 halfword atomics)
  k_count<<<dim3((E + 255) / 256), dim3(256), 0, stream>>>(ei, (u32*)Ac, E);
  // counts -> bf16 in place
  k_cvtA<<<dim3(ZF4 / 256), dim3(256), 0, stream>>>((uint4*)Ac, ZF4);
  // GEMM1: hT[n][m] = bf16(sum_k xb[m][k]*wb[n][k] + bias[n])   (K=2048)
  k_gemm<IN_C, IN_C / 64, 0><<<dim3(88), dim3(256), 0, stream>>>(xb, wb, bias, hT);
  // GEMM2: out[m][n] = sum_k Ac[m][k]*hT[n][k]   (K=2816)
  k_gemm<KP, KP / 64, 1><<<dim3(88), dim3(256), 0, stream>>>(Ac, hT, bias, out);
}

// Round 8
// 147.427 us; speedup vs baseline: 1.3243x; 1.3243x over previous
//
#include <hip/hip_runtime.h>
#include <stdint.h>

typedef unsigned short u16;
typedef unsigned int u32;

#define N_NODES 2708
#define IN_C    2048
#define OUT_C   512
#define MP      2816   // padded node count (multiple of 128)
#define KP      2816   // padded K for gemm2 (= MP)

using floatx4 = __attribute__((ext_vector_type(4))) float;
using short8  = __attribute__((ext_vector_type(8))) short;

// ---- workspace layout (43.9 MB total; 48.2 MB proven available in R0-R2) ----
constexpr size_t XB_OFF = 0;
constexpr size_t XB_SZ  = (size_t)MP * IN_C * 2;      // 11,534,336
constexpr size_t WB_OFF = XB_OFF + XB_SZ;
constexpr size_t WB_SZ  = (size_t)OUT_C * IN_C * 2;   //  2,097,152
constexpr size_t HT_OFF = WB_OFF + WB_SZ;
constexpr size_t HT_SZ  = (size_t)OUT_C * MP * 2;     //  2,883,584
constexpr size_t AC_OFF = HT_OFF + HT_SZ;             // 16,515,072
constexpr size_t AC_SZ  = (size_t)MP * KP * 2;        // 15,859,712
constexpr size_t P_OFF  = AC_OFF + AC_SZ;             // 32,374,784
constexpr size_t P_SZ   = (size_t)2 * OUT_C * MP * 4; // 11,534,336 (P1 and P2 share)

static __device__ __forceinline__ u16 f2bf(float f) {
  union { float f; u32 u; } v; v.f = f;
  u32 r = v.u + 0x7fffu + ((v.u >> 16) & 1u);  // RNE
  return (u16)(r >> 16);
}

// ---- fused prep: x -> bf16 (padded rows), w -> bf16, zero Ac ----
constexpr int XBLK = MP * IN_C / 8 / 256;              // 2816 (block b == row b)
constexpr int WBLK = OUT_C * IN_C / 8 / 256;           // 512
constexpr int ZF4  = (int)(AC_SZ / 16);                // 991,232
constexpr int ZBLK = ZF4 / 256;                        // 3872 (exact)
constexpr int PREP_BLK = XBLK + WBLK + ZBLK;           // 7200

__global__ void k_prep(const float* __restrict__ x, const float* __restrict__ w,
                       u16* __restrict__ xb, u16* __restrict__ wb,
                       float4* __restrict__ zac) {
  const int b = blockIdx.x, tid = threadIdx.x;
  if (b < XBLK) {
    const int row = b, col = tid * 8;
    union { u16 u[8]; uint4 v; } o;
    if (row < N_NODES) {
      float4 v0 = *(const float4*)&x[(size_t)row * IN_C + col];
      float4 v1 = *(const float4*)&x[(size_t)row * IN_C + col + 4];
      o.u[0]=f2bf(v0.x); o.u[1]=f2bf(v0.y); o.u[2]=f2bf(v0.z); o.u[3]=f2bf(v0.w);
      o.u[4]=f2bf(v1.x); o.u[5]=f2bf(v1.y); o.u[6]=f2bf(v1.z); o.u[7]=f2bf(v1.w);
    } else {
      o.v = make_uint4(0, 0, 0, 0);
    }
    *(uint4*)&xb[(size_t)row * IN_C + col] = o.v;
  } else if (b < XBLK + WBLK) {
    const int idx = ((b - XBLK) * 256 + tid) * 8;
    float4 v0 = *(const float4*)&w[idx];
    float4 v1 = *(const float4*)&w[idx + 4];
    union { u16 u[8]; uint4 v; } o;
    o.u[0]=f2bf(v0.x); o.u[1]=f2bf(v0.y); o.u[2]=f2bf(v0.z); o.u[3]=f2bf(v0.w);
    o.u[4]=f2bf(v1.x); o.u[5]=f2bf(v1.y); o.u[6]=f2bf(v1.z); o.u[7]=f2bf(v1.w);
    *(uint4*)&wb[idx] = o.v;
  } else {
    const int i = (b - XBLK - WBLK) * 256 + tid;
    zac[i] = make_float4(0.f, 0.f, 0.f, 0.f);
  }
}

// ---- edge counts into u16 halfwords via u32 atomics ----
__global__ void k_count(const int* __restrict__ ei, u32* __restrict__ Ac, int E) {
  int e = blockIdx.x * 256 + threadIdx.x;
  if (e < E) {
    int src = ei[e];
    int dst = ei[E + e];
    u32 idx = (u32)dst * KP + (u32)src;  // u16 element index
    atomicAdd(&Ac[idx >> 1], 1u << ((idx & 1) * 16));
  }
}

// ---- in-place u16 count -> bf16 (exact for counts <= 256) ----
static __device__ __forceinline__ u32 cvt2(u32 w) {
  float lo = (float)(w & 0xffffu), hi = (float)(w >> 16);
  return (u32)f2bf(lo) | ((u32)f2bf(hi) << 16);
}
__global__ void k_cvtA(uint4* __restrict__ A, int n) {
  int i = blockIdx.x * 256 + threadIdx.x;
  if (i < n) {
    uint4 v = A[i];
    A[i] = make_uint4(cvt2(v.x), cvt2(v.y), cvt2(v.z), cvt2(v.w));
  }
}

// ---- GEMM: P[ks] partial of C[m][n] = sum_k A[m][k]*B[n][k], bf16, ld=LDK.
// BM=128 BN=64 BK=64, KS=2 K-split (f32 partials, NO atomics -- R3 lesson),
// 4 waves 2x2 (wave tile 64x32, acc[4][2]). Grid 352 (8 bn x 22 bm x 2 ks):
// LDS 3x24=72 KB -> 2 blocks/CU, 8 waves/CU (R7's 1 blk/CU latency exposure
// fixed) while keeping staging redundancy moderate (A x8, B x22).
// T4 counted-vmcnt pipeline: 3 LDS buffers, STAGE 2 ahead, vmcnt(6) mid-loop.
// T2 both-sides swizzle (rule #21), XCD-bijective swizzle (352 % 8 == 0),
// T5 setprio around MFMA.
// EPI=0: dst = P1 f32 [KS][OUT_C][MP], float4 stores (transposed).
// EPI=1: dst = P2 f32 [KS][MP][OUT_C], scalar stores (padded rows, no guard).
template<int LDK, int NKI, int EPI>
__global__ __launch_bounds__(256, 2) void k_gemm(
    const u16* __restrict__ A, const u16* __restrict__ B, float* __restrict__ dst) {
  __shared__ u16 lA[3][128 * 64];
  __shared__ u16 lB[3][64 * 64];
  const int tid = threadIdx.x, lane = tid & 63, wid = tid >> 6;

  // XCD swizzle: 44 consecutive swz per XCD -> ~5.5 A-panels + all B panels
  // resident per XCD L2 (~2.4-3.3 MB < 4 MB).
  const int cpx = (int)gridDim.x >> 3;          // 44
  const int orig = blockIdx.x;
  const int swz = (orig & 7) * cpx + (orig >> 3);
  const int bn = swz & 7;
  const int rest = swz >> 3;                    // 0..43
  const int ks = (rest >= 22) ? 1 : 0;
  const int bm = rest - ks * 22;
  const int bmr = bm * 128, bnr = bn * 64;
  const long k0b = (long)ks * LDK;              // K byte-offset (LDK/2 elems * 2B)

  const int wr = wid >> 1, wc = wid & 1;

  // staging: chunk c = 1024B = 8 tile rows; lane l -> row 8c+(l>>3),
  // 16B slot (l&7) XOR'd by row&7 = (l>>3) (pre-swizzled global source).
  // A: 16 chunks (wave w -> {w+4j}); B: 8 chunks (wave w -> {w, w+4}).
  const int swzl = ((lane & 7) ^ ((lane >> 3) & 7)) * 16;
  const char* ag[4];
  const char* bg[2];
#pragma unroll
  for (int j = 0; j < 4; ++j) {
    int c = wid + 4 * j, row = 8 * c + (lane >> 3);
    ag[j] = (const char*)A + (size_t)(bmr + row) * (LDK * 2) + k0b + swzl;
  }
#pragma unroll
  for (int j = 0; j < 2; ++j) {
    int c = wid + 4 * j, row = 8 * c + (lane >> 3);
    bg[j] = (const char*)B + (size_t)(bnr + row) * (LDK * 2) + k0b + swzl;
  }

  // 6 global_load_lds per thread per STAGE (4 A + 2 B) -> vmcnt units of 6
#define STAGE(bb, tt) do {                                                        \
  _Pragma("unroll")                                                               \
  for (int j = 0; j < 4; ++j)                                                     \
    __builtin_amdgcn_global_load_lds(                                             \
      (const __attribute__((address_space(1))) u32*)(ag[j] + (size_t)(tt) * 128), \
      (__attribute__((address_space(3))) u32*)&lA[bb][(wid + 4 * j) * 512],       \
      16, 0, 0);                                                                  \
  _Pragma("unroll")                                                               \
  for (int j = 0; j < 2; ++j)                                                     \
    __builtin_amdgcn_global_load_lds(                                             \
      (const __attribute__((address_space(1))) u32*)(bg[j] + (size_t)(tt) * 128), \
      (__attribute__((address_space(3))) u32*)&lB[bb][(wid + 4 * j) * 512],       \
      16, 0, 0);                                                                  \
} while (0)

  floatx4 acc[4][2] = {};

  STAGE(0, 0);
  if (NKI > 1) STAGE(1, 1);
  int cur = 0;
  for (int t = 0; t < NKI; ++t) {
    // wait for stage(t) only: leaves stage(t+1)'s 6 loads in flight
    if (t + 1 < NKI) asm volatile("s_waitcnt vmcnt(6)" ::: "memory");
    else             asm volatile("s_waitcnt vmcnt(0)" ::: "memory");
    __builtin_amdgcn_s_barrier();
    asm volatile("" ::: "memory");           // fence: keep ds_reads below barrier
    if (t + 2 < NKI) {
      int nb = cur + 2; if (nb >= 3) nb -= 3;
      STAGE(nb, t + 2);                      // overwrites buf consumed at t-1: safe
    }
    const u16* pA = lA[cur];
    const u16* pB = lB[cur];
    short8 af[4][2], bf[2][2];
    // read-side swizzle: slot' = slot ^ (row&7); row&7 == lane&7 for A and B.
#pragma unroll
    for (int mi = 0; mi < 4; ++mi)
#pragma unroll
      for (int kk = 0; kk < 2; ++kk) {
        const int row = wr * 64 + mi * 16 + (lane & 15);
        const int col8 = ((kk * 4 + (lane >> 4)) ^ (lane & 7)) * 8;
        af[mi][kk] = *(const short8*)&pA[row * 64 + col8];
      }
#pragma unroll
    for (int ni = 0; ni < 2; ++ni)
#pragma unroll
      for (int kk = 0; kk < 2; ++kk) {
        const int row = wc * 32 + ni * 16 + (lane & 15);
        const int col8 = ((kk * 4 + (lane >> 4)) ^ (lane & 7)) * 8;
        bf[ni][kk] = *(const short8*)&pB[row * 64 + col8];
      }
    __builtin_amdgcn_s_setprio(1);
#pragma unroll
    for (int kk = 0; kk < 2; ++kk)
#pragma unroll
      for (int mi = 0; mi < 4; ++mi)
#pragma unroll
        for (int ni = 0; ni < 2; ++ni)
          acc[mi][ni] = __builtin_amdgcn_mfma_f32_16x16x32_bf16(af[mi][kk], bf[ni][kk], acc[mi][ni], 0, 0, 0);
    __builtin_amdgcn_s_setprio(0);
    ++cur; if (cur >= 3) cur -= 3;
  }
#undef STAGE

  const int lr = (lane >> 4) * 4, lc = lane & 15;
  if (EPI == 0) {
    // P1[ks][n][m] f32, rows m contiguous -> float4 stores
#pragma unroll
    for (int ni = 0; ni < 2; ++ni) {
      const int n = bnr + wc * 32 + ni * 16 + lc;
#pragma unroll
      for (int mi = 0; mi < 4; ++mi) {
        const int m0 = bmr + wr * 64 + mi * 16 + lr;
        *(floatx4*)&dst[((size_t)ks * OUT_C + n) * MP + m0] = acc[mi][ni];
      }
    }
  } else {
    // P2[ks][m][n] f32 (padded rows; red2 ignores m >= N_NODES)
#pragma unroll
    for (int mi = 0; mi < 4; ++mi)
#pragma unroll
      for (int j = 0; j < 4; ++j) {
        const int m = bmr + wr * 64 + mi * 16 + lr + j;
#pragma unroll
        for (int ni = 0; ni < 2; ++ni) {
          const int n = bnr + wc * 32 + ni * 16 + lc;
          dst[((size_t)ks * MP + m) * OUT_C + n] = acc[mi][ni][j];
        }
      }
  }
}

// ---- red1: hT[n][m] = bf16(P1[0][n][m] + P1[1][n][m] + bias[n]) ----
__global__ void k_red1(const float* __restrict__ P1, const float* __restrict__ bias,
                       u16* __restrict__ hT) {
  int i8 = blockIdx.x * 256 + threadIdx.x;       // [0, OUT_C * MP/8)
  int n = i8 / (MP / 8);
  int m0 = (i8 - n * (MP / 8)) * 8;
  float bv = bias[n];
  const float* p0 = &P1[(size_t)n * MP + m0];
  const float* p1 = p0 + (size_t)OUT_C * MP;
  float4 a0 = *(const float4*)p0, a1 = *(const float4*)(p0 + 4);
  float4 b0 = *(const float4*)p1, b1 = *(const float4*)(p1 + 4);
  union { u16 u[8]; uint4 v; } o;
  o.u[0]=f2bf(a0.x+b0.x+bv); o.u[1]=f2bf(a0.y+b0.y+bv);
  o.u[2]=f2bf(a0.z+b0.z+bv); o.u[3]=f2bf(a0.w+b0.w+bv);
  o.u[4]=f2bf(a1.x+b1.x+bv); o.u[5]=f2bf(a1.y+b1.y+bv);
  o.u[6]=f2bf(a1.z+b1.z+bv); o.u[7]=f2bf(a1.w+b1.w+bv);
  *(uint4*)&hT[(size_t)n * MP + m0] = o.v;
}

// ---- red2: out[m][n] = P2[0][m][n] + P2[1][m][n], m < N_NODES ----
__global__ void k_red2(const float* __restrict__ P2, float* __restrict__ out) {
  int i = blockIdx.x * 256 + threadIdx.x;        // [0, N_NODES*OUT_C/4) exact
  size_t o = (size_t)i * 4;
  float4 a = *(const float4*)&P2[o];
  float4 b = *(const float4*)&P2[(size_t)MP * OUT_C + o];
  *(float4*)&out[o] = make_float4(a.x + b.x, a.y + b.y, a.z + b.z, a.w + b.w);
}

extern "C" void kernel_launch(void* const* d_in, const int* in_sizes, int n_in,
                              void* d_out, int out_size, void* d_ws, size_t ws_size,
                              hipStream_t stream) {
  const float* x    = (const float*)d_in[0];
  const int*   ei   = (const int*)d_in[1];
  const float* w    = (const float*)d_in[2];
  const float* bias = (const float*)d_in[3];
  float* out = (float*)d_out;

  char* ws = (char*)d_ws;
  u16*   xb = (u16*)(ws + XB_OFF);
  u16*   wb = (u16*)(ws + WB_OFF);
  u16*   hT = (u16*)(ws + HT_OFF);
  u16*   Ac = (u16*)(ws + AC_OFF);   // u16 counts, then bf16 in-place
  float* P  = (float*)(ws + P_OFF);  // P1 [2][512][2816] then P2 [2][2816][512]

  const int E = in_sizes[1] / 2;  // 500000

  // prep: x->bf16(padded), w->bf16, zero Ac
  k_prep<<<dim3(PREP_BLK), dim3(256), 0, stream>>>(x, w, xb, wb, (float4*)Ac);
  // edge counts (u16 halfword atomics)
  k_count<<<dim3((E + 255) / 256), dim3(256), 0, stream>>>(ei, (u32*)Ac, E);
  // counts -> bf16 in place
  k_cvtA<<<dim3(ZF4 / 256), dim3(256), 0, stream>>>((uint4*)Ac, ZF4);
  // GEMM1 partials: P1[ks][n][m] = sum_{k in ks} xb[m][k]*wb[n][k]
  k_gemm<IN_C, IN_C / 2 / 64, 0><<<dim3(352), dim3(256), 0, stream>>>(xb, wb, P);
  // reduce + bias -> hT bf16
  k_red1<<<dim3(OUT_C * MP / 8 / 256), dim3(256), 0, stream>>>(P, bias, hT);
  // GEMM2 partials: P2[ks][m][n] = sum_{k in ks} Ac[m][k]*hT[n][k]
  k_gemm<KP, KP / 2 / 64, 1><<<dim3(352), dim3(256), 0, stream>>>(Ac, hT, P);
  // reduce -> out
  k_red2<<<dim3(N_NODES * OUT_C / 4 / 256), dim3(256), 0, stream>>>(P, out);
}